// Round 2
// baseline (4076.170 us; speedup 1.0000x reference)
//
#include <hip/hip_runtime.h>
#include <math.h>

// Swin-3D basic layer: 2 blocks (non-shifted, shifted).
// S=32,H=64,W=64, C=192, NH=6, HD=32, window 4x4x4 (N=64), shift 2, NWIN=2048, L=131072.
// fp32 baseline: tiled fp32 GEMMs + fused window/shift/LN/bias/gelu/residual epilogues.
// Workspace budget: 4P floats (P = L*C) = 402 MB. x2 aliases d_out (elementwise-safe),
// MLP hidden is processed in 2 row-chunks reusing the dead q/k/v region.

#define L_TOK 131072
#define C_DIM 192
#define NHEAD 6
#define HDIM 32
#define NWIN 2048
#define NTOK 64
#define TILE_K 32
#define MLP_CHUNK_ROWS 65536

// ---------------------------------------------------------------------------
// helpers
// ---------------------------------------------------------------------------

// window-ordered row r (win*64+n) -> natural token index, with optional shift.
// Rolled frame: rolled[g] = orig[(g+shift)%D].
__device__ __forceinline__ int win_row_to_token(int r, int shifted) {
    const int win = r >> 6, n = r & 63;
    const int sb = win >> 8, hb = (win >> 4) & 15, wb = win & 15;
    int gz = sb * 4 + (n >> 4);
    int gy = hb * 4 + ((n >> 2) & 3);
    int gx = wb * 4 + (n & 3);
    if (shifted) { gz = (gz + 2) & 31; gy = (gy + 2) & 63; gx = (gx + 2) & 63; }
    return (gz << 12) | (gy << 6) | gx;
}

// ---------------------------------------------------------------------------
// LayerNorm (+optional window partition / shift gather)
// mode 0: partition, no shift; mode 1: partition + shift; mode 2: identity rows
// one wave per token; 4 tokens per 256-thread block
// ---------------------------------------------------------------------------
__global__ __launch_bounds__(256) void ln_kernel(const float* __restrict__ x,
                                                 const float* __restrict__ g,
                                                 const float* __restrict__ b,
                                                 float* __restrict__ out, int mode) {
    const int r = blockIdx.x * 4 + (threadIdx.x >> 6);
    const int lane = threadIdx.x & 63;
    const int tin = (mode == 2) ? r : win_row_to_token(r, mode);
    const float* xr = x + (size_t)tin * C_DIM;
    const float v0 = xr[lane], v1 = xr[lane + 64], v2 = xr[lane + 128];
    float s = v0 + v1 + v2;
#pragma unroll
    for (int off = 32; off >= 1; off >>= 1) s += __shfl_xor(s, off, 64);
    const float mu = s * (1.0f / 192.0f);
    const float d0 = v0 - mu, d1 = v1 - mu, d2 = v2 - mu;
    float sq = d0 * d0 + d1 * d1 + d2 * d2;
#pragma unroll
    for (int off = 32; off >= 1; off >>= 1) sq += __shfl_xor(sq, off, 64);
    const float rstd = rsqrtf(sq * (1.0f / 192.0f) + 1e-5f);
    float* orow = out + (size_t)r * C_DIM;
    orow[lane]       = d0 * rstd * g[lane]       + b[lane];
    orow[lane + 64]  = d1 * rstd * g[lane + 64]  + b[lane + 64];
    orow[lane + 128] = d2 * rstd * g[lane + 128] + b[lane + 128];
}

// ---------------------------------------------------------------------------
// fp32 GEMM core: 64x64 tile, BK=32, 256 threads, 4x4 acc per thread.
// A row-major (64 x KTOT, lda), B row-major (KTOT x >=64, ldb).
// As transposed [k][m] pad 68; Bs [k][n] stride 64.
// ---------------------------------------------------------------------------
template <int KTOT>
__device__ __forceinline__ void gemm_core(const float* __restrict__ A, int lda,
                                          const float* __restrict__ B, int ldb,
                                          float (&acc)[4][4], float* As, float* Bs) {
    const int tid = threadIdx.x;
    const int tx = tid & 15, ty = tid >> 4;
    const int arow = tid >> 2;
    const int acol = (tid & 3) << 3;
    const int brow = tid >> 4;
    const int bcol = (tid & 15) << 2;
#pragma unroll 1
    for (int k0 = 0; k0 < KTOT; k0 += TILE_K) {
#pragma unroll
        for (int u = 0; u < 2; ++u) {
            const int c = acol + u * 4;
            const float4 a4 = *(const float4*)(A + (size_t)arow * lda + k0 + c);
            As[(c + 0) * 68 + arow] = a4.x;
            As[(c + 1) * 68 + arow] = a4.y;
            As[(c + 2) * 68 + arow] = a4.z;
            As[(c + 3) * 68 + arow] = a4.w;
        }
#pragma unroll
        for (int u = 0; u < 2; ++u) {
            const int rr = u * 16 + brow;
            const float4 b4 = *(const float4*)(B + (size_t)(k0 + rr) * ldb + bcol);
            *(float4*)(Bs + rr * 64 + bcol) = b4;
        }
        __syncthreads();
#pragma unroll
        for (int kk = 0; kk < TILE_K; ++kk) {
            const float4 av = *(const float4*)(As + kk * 68 + (ty << 2));
            const float4 bv = *(const float4*)(Bs + kk * 64 + (tx << 2));
            const float a0 = av.x, a1 = av.y, a2 = av.z, a3 = av.w;
            const float b0 = bv.x, b1 = bv.y, b2 = bv.z, b3 = bv.w;
            acc[0][0] = fmaf(a0, b0, acc[0][0]); acc[0][1] = fmaf(a0, b1, acc[0][1]);
            acc[0][2] = fmaf(a0, b2, acc[0][2]); acc[0][3] = fmaf(a0, b3, acc[0][3]);
            acc[1][0] = fmaf(a1, b0, acc[1][0]); acc[1][1] = fmaf(a1, b1, acc[1][1]);
            acc[1][2] = fmaf(a1, b2, acc[1][2]); acc[1][3] = fmaf(a1, b3, acc[1][3]);
            acc[2][0] = fmaf(a2, b0, acc[2][0]); acc[2][1] = fmaf(a2, b1, acc[2][1]);
            acc[2][2] = fmaf(a2, b2, acc[2][2]); acc[2][3] = fmaf(a2, b3, acc[2][3]);
            acc[3][0] = fmaf(a3, b0, acc[3][0]); acc[3][1] = fmaf(a3, b1, acc[3][1]);
            acc[3][2] = fmaf(a3, b2, acc[3][2]); acc[3][3] = fmaf(a3, b3, acc[3][3]);
        }
        __syncthreads();
    }
}

// ---------------------------------------------------------------------------
// QKV GEMM: xw(L x 192) @ qw(192 x 576) + qb -> q,k,v [win][head][n][hd]
// q pre-scaled by HD^-0.5. grid (2048, 9)
// ---------------------------------------------------------------------------
__global__ __launch_bounds__(256) void qkv_gemm_kernel(const float* __restrict__ xw,
                                                       const float* __restrict__ qw,
                                                       const float* __restrict__ qb,
                                                       float* __restrict__ qo,
                                                       float* __restrict__ ko,
                                                       float* __restrict__ vo) {
    __shared__ float As[TILE_K * 68];
    __shared__ float Bs[TILE_K * 64];
    float acc[4][4] = {};
    const int m0 = blockIdx.x * 64, n0 = blockIdx.y * 64;
    gemm_core<192>(xw + (size_t)m0 * C_DIM, C_DIM, qw + n0, 576, acc, As, Bs);
    const int tx = threadIdx.x & 15, ty = threadIdx.x >> 4;
    const int jc = n0 + tx * 4;        // same (which,head) for the 4 cols
    const int which = jc / 192;
    const int head = (jc % 192) >> 5;
    const int hd0 = jc & 31;
    float* dst = (which == 0) ? qo : ((which == 1) ? ko : vo);
    const float scale = (which == 0) ? 0.17677669529663687f : 1.0f;
    const float4 bias = *(const float4*)(qb + jc);
#pragma unroll
    for (int i = 0; i < 4; ++i) {
        const int m = m0 + ty * 4 + i;
        const int win = m >> 6, n = m & 63;
        float4 r;
        r.x = (acc[i][0] + bias.x) * scale;
        r.y = (acc[i][1] + bias.y) * scale;
        r.z = (acc[i][2] + bias.z) * scale;
        r.w = (acc[i][3] + bias.w) * scale;
        *(float4*)(dst + ((size_t)(win * NHEAD + head) * NTOK + n) * HDIM + hd0) = r;
    }
}

// ---------------------------------------------------------------------------
// attention: one block per (win, head). QK^T + bias + shift mask + softmax + PV
// grid 12288: head = bx>>11, win = bx&2047
// ---------------------------------------------------------------------------
__global__ __launch_bounds__(256) void attn_kernel(const float* __restrict__ qg,
                                                   const float* __restrict__ kg,
                                                   const float* __restrict__ vg,
                                                   const float* __restrict__ rpb,
                                                   float* __restrict__ o, int shifted) {
    __shared__ float qs[64 * 33];
    __shared__ float ks[64 * 33];
    __shared__ float vs[64 * 36];
    __shared__ float ps[64 * 68];
    __shared__ float bias_s[343];
    __shared__ float inv_s[64];
    __shared__ int ms[64];
    const int tid = threadIdx.x;
    const int head = blockIdx.x >> 11;
    const int win = blockIdx.x & 2047;
    const size_t base = (size_t)(win * NHEAD + head) * (NTOK * HDIM);
    {
        const int f = tid * 8;
        const int n = f >> 5, hd = f & 31;
        float4 a = *(const float4*)(qg + base + f);
        float4 b4 = *(const float4*)(qg + base + f + 4);
        float* p = qs + n * 33 + hd;
        p[0]=a.x; p[1]=a.y; p[2]=a.z; p[3]=a.w; p[4]=b4.x; p[5]=b4.y; p[6]=b4.z; p[7]=b4.w;
        a = *(const float4*)(kg + base + f);
        b4 = *(const float4*)(kg + base + f + 4);
        p = ks + n * 33 + hd;
        p[0]=a.x; p[1]=a.y; p[2]=a.z; p[3]=a.w; p[4]=b4.x; p[5]=b4.y; p[6]=b4.z; p[7]=b4.w;
        a = *(const float4*)(vg + base + f);
        b4 = *(const float4*)(vg + base + f + 4);
        p = vs + n * 36 + hd;
        p[0]=a.x; p[1]=a.y; p[2]=a.z; p[3]=a.w; p[4]=b4.x; p[5]=b4.y; p[6]=b4.z; p[7]=b4.w;
    }
    for (int idx = tid; idx < 343; idx += 256) bias_s[idx] = rpb[idx * NHEAD + head];
    if (tid < 64) {
        int mv = 0;
        if (shifted) {
            const int sb = win >> 8, hb = (win >> 4) & 15, wb = win & 15;
            const int gz = sb * 4 + (tid >> 4);
            const int gy = hb * 4 + ((tid >> 2) & 3);
            const int gx = wb * 4 + (tid & 3);
            const int rz = gz < 28 ? 0 : (gz < 30 ? 1 : 2);
            const int ry = gy < 60 ? 0 : (gy < 62 ? 1 : 2);
            const int rw = gx < 60 ? 0 : (gx < 62 ? 1 : 2);
            mv = rz * 9 + ry * 3 + rw;
        }
        ms[tid] = mv;
    }
    __syncthreads();
    // --- QK^T (q already scaled) ---
    const int tx = tid & 15, ty = tid >> 4;
    float a16[4][4] = {};
#pragma unroll
    for (int d = 0; d < 32; ++d) {
        float qa[4], kb[4];
#pragma unroll
        for (int ii = 0; ii < 4; ++ii) qa[ii] = qs[(ty * 4 + ii) * 33 + d];
#pragma unroll
        for (int jj = 0; jj < 4; ++jj) kb[jj] = ks[(tx * 4 + jj) * 33 + d];
#pragma unroll
        for (int ii = 0; ii < 4; ++ii)
#pragma unroll
            for (int jj = 0; jj < 4; ++jj) a16[ii][jj] = fmaf(qa[ii], kb[jj], a16[ii][jj]);
    }
#pragma unroll
    for (int ii = 0; ii < 4; ++ii) {
#pragma unroll
        for (int jj = 0; jj < 4; ++jj) {
            const int i = ty * 4 + ii, j = tx * 4 + jj;
            const int dz = (i >> 4) - (j >> 4) + 3;
            const int dy = ((i >> 2) & 3) - ((j >> 2) & 3) + 3;
            const int dx = (i & 3) - (j & 3) + 3;
            float val = a16[ii][jj] + bias_s[dz * 49 + dy * 7 + dx];
            if (shifted && (ms[i] != ms[j])) val -= 100.0f;
            ps[i * 68 + j] = val;
        }
    }
    __syncthreads();
    // --- softmax (4 lanes per row) ---
    {
        const int r = tid >> 2, sub = tid & 3;
        float* row = ps + r * 68 + sub * 16;
        float mx = -3.0e38f;
#pragma unroll
        for (int jj = 0; jj < 16; ++jj) mx = fmaxf(mx, row[jj]);
        mx = fmaxf(mx, __shfl_xor(mx, 1, 64));
        mx = fmaxf(mx, __shfl_xor(mx, 2, 64));
        float sum = 0.0f;
#pragma unroll
        for (int jj = 0; jj < 16; ++jj) {
            const float e = expf(row[jj] - mx);
            row[jj] = e;
            sum += e;
        }
        sum += __shfl_xor(sum, 1, 64);
        sum += __shfl_xor(sum, 2, 64);
        if (sub == 0) inv_s[r] = 1.0f / sum;
    }
    __syncthreads();
    // --- PV: thread owns (row i, 8 of 32 dims) ---
    {
        const int i = tid >> 2, d0 = (tid & 3) * 8;
        float av[8] = {};
        const float* prow = ps + i * 68;
#pragma unroll
        for (int j = 0; j < 64; ++j) {
            const float p = prow[j];
            const float4 va = *(const float4*)(vs + j * 36 + d0);
            const float4 vb = *(const float4*)(vs + j * 36 + d0 + 4);
            av[0] = fmaf(p, va.x, av[0]); av[1] = fmaf(p, va.y, av[1]);
            av[2] = fmaf(p, va.z, av[2]); av[3] = fmaf(p, va.w, av[3]);
            av[4] = fmaf(p, vb.x, av[4]); av[5] = fmaf(p, vb.y, av[5]);
            av[6] = fmaf(p, vb.z, av[6]); av[7] = fmaf(p, vb.w, av[7]);
        }
        const float inv = inv_s[i];
        float4 r0, r1;
        r0.x = av[0] * inv; r0.y = av[1] * inv; r0.z = av[2] * inv; r0.w = av[3] * inv;
        r1.x = av[4] * inv; r1.y = av[5] * inv; r1.z = av[6] * inv; r1.w = av[7] * inv;
        float* op = o + (size_t)(win * NTOK + i) * C_DIM + head * HDIM + d0;
        *(float4*)op = r0;
        *(float4*)(op + 4) = r1;
    }
}

// ---------------------------------------------------------------------------
// proj GEMM + window reverse + unshift + residual: x2[t] = X[t] + (o@pw+pb)
// Safe when x2 aliases xin: each [t][jc] element is read then written by the
// same thread only. grid (2048, 3)
// ---------------------------------------------------------------------------
__global__ __launch_bounds__(256) void proj_gemm_kernel(const float* __restrict__ o,
                                                        const float* __restrict__ pw,
                                                        const float* __restrict__ pb,
                                                        const float* xin,
                                                        float* x2, int shifted) {
    __shared__ float As[TILE_K * 68];
    __shared__ float Bs[TILE_K * 64];
    float acc[4][4] = {};
    const int m0 = blockIdx.x * 64, n0 = blockIdx.y * 64;
    gemm_core<192>(o + (size_t)m0 * C_DIM, C_DIM, pw + n0, C_DIM, acc, As, Bs);
    const int tx = threadIdx.x & 15, ty = threadIdx.x >> 4;
    const int jc = n0 + tx * 4;
    const float4 bias = *(const float4*)(pb + jc);
#pragma unroll
    for (int i = 0; i < 4; ++i) {
        const int m = m0 + ty * 4 + i;
        const int t = win_row_to_token(m, shifted);
        const float4 sc = *(const float4*)(xin + (size_t)t * C_DIM + jc);
        float4 r;
        r.x = acc[i][0] + bias.x + sc.x;
        r.y = acc[i][1] + bias.y + sc.y;
        r.z = acc[i][2] + bias.z + sc.z;
        r.w = acc[i][3] + bias.w + sc.w;
        *(float4*)(x2 + (size_t)t * C_DIM + jc) = r;
    }
}

// ---------------------------------------------------------------------------
// FC1 + exact gelu on a row chunk: h = gelu(x2n @ f1w + f1b). grid (1024, 12)
// ---------------------------------------------------------------------------
__global__ __launch_bounds__(256) void fc1_gemm_kernel(const float* __restrict__ x2n,
                                                       const float* __restrict__ f1w,
                                                       const float* __restrict__ f1b,
                                                       float* __restrict__ h,
                                                       int row_off) {
    __shared__ float As[TILE_K * 68];
    __shared__ float Bs[TILE_K * 64];
    float acc[4][4] = {};
    const int m0 = blockIdx.x * 64, n0 = blockIdx.y * 64;
    gemm_core<192>(x2n + (size_t)(row_off + m0) * C_DIM, C_DIM, f1w + n0, 768, acc, As, Bs);
    const int tx = threadIdx.x & 15, ty = threadIdx.x >> 4;
    const int jc = n0 + tx * 4;
    const float4 bias = *(const float4*)(f1b + jc);
#pragma unroll
    for (int i = 0; i < 4; ++i) {
        const int m = m0 + ty * 4 + i;   // chunk-local row
        float t0 = acc[i][0] + bias.x, t1 = acc[i][1] + bias.y;
        float t2 = acc[i][2] + bias.z, t3 = acc[i][3] + bias.w;
        float4 r;
        r.x = 0.5f * t0 * (1.0f + erff(t0 * 0.7071067811865475f));
        r.y = 0.5f * t1 * (1.0f + erff(t1 * 0.7071067811865475f));
        r.z = 0.5f * t2 * (1.0f + erff(t2 * 0.7071067811865475f));
        r.w = 0.5f * t3 * (1.0f + erff(t3 * 0.7071067811865475f));
        *(float4*)(h + (size_t)m * 768 + jc) = r;
    }
}

// ---------------------------------------------------------------------------
// FC2 + residual on a row chunk: out = x2 + h @ f2w + f2b.
// Safe when out aliases x2 (same-element RMW per thread). grid (1024, 3)
// ---------------------------------------------------------------------------
__global__ __launch_bounds__(256) void fc2_gemm_kernel(const float* __restrict__ h,
                                                       const float* __restrict__ f2w,
                                                       const float* __restrict__ f2b,
                                                       const float* x2,
                                                       float* out, int row_off) {
    __shared__ float As[TILE_K * 68];
    __shared__ float Bs[TILE_K * 64];
    float acc[4][4] = {};
    const int m0 = blockIdx.x * 64, n0 = blockIdx.y * 64;
    gemm_core<768>(h + (size_t)m0 * 768, 768, f2w + n0, C_DIM, acc, As, Bs);
    const int tx = threadIdx.x & 15, ty = threadIdx.x >> 4;
    const int jc = n0 + tx * 4;
    const float4 bias = *(const float4*)(f2b + jc);
#pragma unroll
    for (int i = 0; i < 4; ++i) {
        const int m = m0 + ty * 4 + i;   // chunk-local row
        const size_t g = (size_t)(row_off + m) * C_DIM + jc;
        const float4 sc = *(const float4*)(x2 + g);
        float4 r;
        r.x = acc[i][0] + bias.x + sc.x;
        r.y = acc[i][1] + bias.y + sc.y;
        r.z = acc[i][2] + bias.z + sc.z;
        r.w = acc[i][3] + bias.w + sc.w;
        *(float4*)(out + g) = r;
    }
}

// ---------------------------------------------------------------------------
// host-side orchestration.
// ws layout (P = L*C floats): [0,P) xw -> o -> x2n ; [P,4P) q,k,v -> h chunks.
// x2 lives in d_out (aliasing-safe as noted above). Total ws need: 4P = 402 MB.
// ---------------------------------------------------------------------------
static void run_block(const float* X, float* XOUT,
                      const float* g1, const float* b1, const float* qw, const float* qb,
                      const float* rpb, const float* pw, const float* pb,
                      const float* g2, const float* b2,
                      const float* f1w, const float* f1b, const float* f2w, const float* f2b,
                      int shifted, float* ws, hipStream_t stream) {
    const size_t P = (size_t)L_TOK * C_DIM;  // 25165824 floats
    float* xw  = ws;           // [0,P): LN'd window-ordered input
    float* q   = ws + P;
    float* k   = ws + 2 * P;
    float* v   = ws + 3 * P;
    float* o   = xw;           // reuse after qkv gemm
    float* x2  = XOUT;         // aliases d_out
    float* x2n = xw;           // reuse after proj
    float* h   = ws + P;       // [P,3P): hidden chunk (q,k,v dead)

    ln_kernel<<<L_TOK / 4, 256, 0, stream>>>(X, g1, b1, xw, shifted ? 1 : 0);
    qkv_gemm_kernel<<<dim3(NWIN, 9), 256, 0, stream>>>(xw, qw, qb, q, k, v);
    attn_kernel<<<NWIN * NHEAD, 256, 0, stream>>>(q, k, v, rpb, o, shifted);
    proj_gemm_kernel<<<dim3(NWIN, 3), 256, 0, stream>>>(o, pw, pb, X, x2, shifted);
    ln_kernel<<<L_TOK / 4, 256, 0, stream>>>(x2, g2, b2, x2n, 2);
    for (int c = 0; c < 2; ++c) {
        const int row_off = c * MLP_CHUNK_ROWS;
        fc1_gemm_kernel<<<dim3(MLP_CHUNK_ROWS / 64, 12), 256, 0, stream>>>(x2n, f1w, f1b, h, row_off);
        fc2_gemm_kernel<<<dim3(MLP_CHUNK_ROWS / 64, 3), 256, 0, stream>>>(h, f2w, f2b, x2, XOUT, row_off);
    }
}

extern "C" void kernel_launch(void* const* d_in, const int* in_sizes, int n_in,
                              void* d_out, int out_size, void* d_ws, size_t ws_size,
                              hipStream_t stream) {
    const float* x = (const float*)d_in[0];
    float* out = (float*)d_out;
    float* ws = (float*)d_ws;
    auto in = [&](int i) { return (const float*)d_in[i]; };

    // block 0 (not shifted): x -> d_out
    run_block(x, out,
              in(1), in(2), in(3), in(4), in(5), in(6), in(7),
              in(8), in(9), in(10), in(11), in(12), in(13),
              0, ws, stream);
    // block 1 (shifted): d_out -> d_out
    run_block(out, out,
              in(14), in(15), in(16), in(17), in(18), in(19), in(20),
              in(21), in(22), in(23), in(24), in(25), in(26),
              1, ws, stream);
}

// Round 3
// 1623.494 us; speedup vs baseline: 2.5107x; 2.5107x over previous
//
#include <hip/hip_runtime.h>
#include <math.h>

// Swin-3D basic layer, bf16-MFMA version.
// S=32,H=64,W=64, C=192, NH=6, HD=32, win 4x4x4 (N=64), shift 2, NWIN=2048, L=131072.
// GEMMs: mfma_f32_16x16x32_bf16, fp32 accum, bf16 activations, fp32 residuals/LN.
// A-stationary tiling (K=192 GEMMs): stage A[128][192] once, loop N-chunks.
// fc2 (K=768): K-loop, full N=192 per block so h is read exactly once.

#define L_TOK 131072
#define C_DIM 192
#define NWIN 2048

typedef unsigned int uint32;
typedef unsigned short u16;
typedef __bf16 bf16x8 __attribute__((ext_vector_type(8)));
typedef float f32x4 __attribute__((ext_vector_type(4)));

__device__ __forceinline__ u16 f2bf(float f) {
    uint32 u = __float_as_uint(f);
    u += 0x7fffu + ((u >> 16) & 1u);
    return (u16)(u >> 16);
}
__device__ __forceinline__ float bf2f(u16 h) { return __uint_as_float(((uint32)h) << 16); }

// window-ordered row r -> natural token index (rolled[g] = orig[(g+shift)%D])
__device__ __forceinline__ int win_row_to_token(int r, int shifted) {
    const int win = r >> 6, n = r & 63;
    const int sb = win >> 8, hb = (win >> 4) & 15, wb = win & 15;
    int gz = sb * 4 + (n >> 4);
    int gy = hb * 4 + ((n >> 2) & 3);
    int gx = wb * 4 + (n & 3);
    if (shifted) { gz = (gz + 2) & 31; gy = (gy + 2) & 63; gx = (gx + 2) & 63; }
    return (gz << 12) | (gy << 6) | gx;
}

// ---------------------------------------------------------------------------
// weight transpose + bf16 convert: in [K][N] fp32 -> out [N][K] bf16
// ---------------------------------------------------------------------------
__global__ __launch_bounds__(256) void wtrans_kernel(const float* __restrict__ in,
                                                     u16* __restrict__ out, int K, int N) {
    const int idx = blockIdx.x * 256 + threadIdx.x;
    if (idx < K * N) {
        const int n = idx / K, k = idx - n * K;
        out[idx] = f2bf(in[(size_t)k * N + n]);
    }
}

// ---------------------------------------------------------------------------
// LayerNorm: fp32 in -> bf16 out. mode 0 partition, 1 partition+shift, 2 identity
// ---------------------------------------------------------------------------
__global__ __launch_bounds__(256) void ln_kernel(const float* __restrict__ x,
                                                 const float* __restrict__ g,
                                                 const float* __restrict__ b,
                                                 u16* __restrict__ out, int mode) {
    const int r = blockIdx.x * 4 + (threadIdx.x >> 6);
    const int lane = threadIdx.x & 63;
    const int tin = (mode == 2) ? r : win_row_to_token(r, mode);
    const float* xr = x + (size_t)tin * C_DIM;
    const float v0 = xr[lane], v1 = xr[lane + 64], v2 = xr[lane + 128];
    float s = v0 + v1 + v2;
#pragma unroll
    for (int off = 32; off >= 1; off >>= 1) s += __shfl_xor(s, off, 64);
    const float mu = s * (1.0f / 192.0f);
    const float d0 = v0 - mu, d1 = v1 - mu, d2 = v2 - mu;
    float sq = d0 * d0 + d1 * d1 + d2 * d2;
#pragma unroll
    for (int off = 32; off >= 1; off >>= 1) sq += __shfl_xor(sq, off, 64);
    const float rstd = rsqrtf(sq * (1.0f / 192.0f) + 1e-5f);
    u16* orow = out + (size_t)r * C_DIM;
    orow[lane]       = f2bf(d0 * rstd * g[lane]       + b[lane]);
    orow[lane + 64]  = f2bf(d1 * rstd * g[lane + 64]  + b[lane + 64]);
    orow[lane + 128] = f2bf(d2 * rstd * g[lane + 128] + b[lane + 128]);
}

// ---------------------------------------------------------------------------
// shared staging helpers for K=192 tiles (row stride 200 u16 = 400B, bank-staggered)
// ---------------------------------------------------------------------------
__device__ __forceinline__ void stage_rows192(const u16* __restrict__ g, u16* __restrict__ s,
                                              int iters) {
    const int tid = threadIdx.x;
#pragma unroll
    for (int i = 0; i < iters; ++i) {
        const int c = tid + 256 * i;
        const int row = c / 24, ko = (c - row * 24) * 8;
        *(uint4*)(s + row * 200 + ko) = *(const uint4*)(g + (size_t)row * 192 + ko);
    }
}

__device__ __forceinline__ void compute192(const u16* __restrict__ As, const u16* __restrict__ Bs,
                                           f32x4 (&acc)[2][4]) {
    const int lane = threadIdx.x & 63, wave = threadIdx.x >> 6;
    const u16* pa = As + (wave * 32 + (lane & 15)) * 200 + ((lane >> 4) * 8);
    const u16* pb = Bs + (lane & 15) * 200 + ((lane >> 4) * 8);
#pragma unroll
    for (int ks = 0; ks < 6; ++ks) {
        const bf16x8 a0 = *(const bf16x8*)(pa + ks * 32);
        const bf16x8 a1 = *(const bf16x8*)(pa + 16 * 200 + ks * 32);
#pragma unroll
        for (int nj = 0; nj < 4; ++nj) {
            const bf16x8 b = *(const bf16x8*)(pb + nj * 16 * 200 + ks * 32);
            acc[0][nj] = __builtin_amdgcn_mfma_f32_16x16x32_bf16(a0, b, acc[0][nj], 0, 0, 0);
            acc[1][nj] = __builtin_amdgcn_mfma_f32_16x16x32_bf16(a1, b, acc[1][nj], 0, 0, 0);
        }
    }
}

// ---------------------------------------------------------------------------
// QKV: xw[M][192]bf16 @ qwT[576][192] -> q,k,v bf16 [win*6+head][64][32], q scaled
// ---------------------------------------------------------------------------
__global__ __launch_bounds__(256) void qkv_mfma(const u16* __restrict__ xw,
                                                const u16* __restrict__ qwT,
                                                const float* __restrict__ qb,
                                                u16* __restrict__ q, u16* __restrict__ k,
                                                u16* __restrict__ v) {
    __shared__ __align__(16) u16 As[128 * 200];
    __shared__ __align__(16) u16 Bs[64 * 200];
    const int m0 = blockIdx.x * 128;
    const int lane = threadIdx.x & 63, wave = threadIdx.x >> 6;
    stage_rows192(xw + (size_t)m0 * 192, As, 12);
#pragma unroll 1
    for (int nc = 0; nc < 9; ++nc) {
        stage_rows192(qwT + (size_t)nc * 64 * 192, Bs, 6);
        __syncthreads();
        f32x4 acc[2][4] = {};
        compute192(As, Bs, acc);
#pragma unroll
        for (int nj = 0; nj < 4; ++nj) {
            const int n = nc * 64 + nj * 16 + (lane & 15);
            const int which = n / 192;
            const int hn = n - which * 192;
            const int head = hn >> 5, hd = hn & 31;
            u16* dst = (which == 0) ? q : (which == 1) ? k : v;
            const float sc = (which == 0) ? 0.17677669529663687f : 1.0f;
            const float bi = qb[n];
#pragma unroll
            for (int mi = 0; mi < 2; ++mi)
#pragma unroll
                for (int r = 0; r < 4; ++r) {
                    const int m = m0 + wave * 32 + mi * 16 + ((lane >> 4) << 2) + r;
                    const int win = m >> 6, tok = m & 63;
                    dst[((size_t)(win * 6 + head) * 64 + tok) * 32 + hd] =
                        f2bf((acc[mi][nj][r] + bi) * sc);
                }
        }
        __syncthreads();
    }
}

// ---------------------------------------------------------------------------
// proj: o[M][192]bf16 @ pwT[192][192] + pb + X(residual) -> x2 fp32 (win-reverse)
// ---------------------------------------------------------------------------
__global__ __launch_bounds__(256) void proj_mfma(const u16* __restrict__ o,
                                                 const u16* __restrict__ pwT,
                                                 const float* __restrict__ pb,
                                                 const float* xin, float* x2, int shifted) {
    __shared__ __align__(16) u16 As[128 * 200];
    __shared__ __align__(16) u16 Bs[64 * 200];
    const int m0 = blockIdx.x * 128;
    const int lane = threadIdx.x & 63, wave = threadIdx.x >> 6;
    stage_rows192(o + (size_t)m0 * 192, As, 12);
#pragma unroll 1
    for (int nc = 0; nc < 3; ++nc) {
        stage_rows192(pwT + (size_t)nc * 64 * 192, Bs, 6);
        __syncthreads();
        f32x4 acc[2][4] = {};
        compute192(As, Bs, acc);
#pragma unroll
        for (int nj = 0; nj < 4; ++nj) {
            const int n = nc * 64 + nj * 16 + (lane & 15);
            const float bi = pb[n];
#pragma unroll
            for (int mi = 0; mi < 2; ++mi)
#pragma unroll
                for (int r = 0; r < 4; ++r) {
                    const int m = m0 + wave * 32 + mi * 16 + ((lane >> 4) << 2) + r;
                    const int t = win_row_to_token(m, shifted);
                    const size_t gdx = (size_t)t * C_DIM + n;
                    x2[gdx] = xin[gdx] + bi + acc[mi][nj][r];
                }
        }
        __syncthreads();
    }
}

// ---------------------------------------------------------------------------
// fc1: x2n[M][192]bf16 @ f1wT[768][192] + f1b, exact gelu -> h[M][768] bf16
// ---------------------------------------------------------------------------
__global__ __launch_bounds__(256) void fc1_mfma(const u16* __restrict__ x2n,
                                                const u16* __restrict__ f1wT,
                                                const float* __restrict__ f1b,
                                                u16* __restrict__ h) {
    __shared__ __align__(16) u16 As[128 * 200];
    __shared__ __align__(16) u16 Bs[64 * 200];
    const int m0 = blockIdx.x * 128;
    const int lane = threadIdx.x & 63, wave = threadIdx.x >> 6;
    stage_rows192(x2n + (size_t)m0 * 192, As, 12);
#pragma unroll 1
    for (int nc = 0; nc < 12; ++nc) {
        stage_rows192(f1wT + (size_t)nc * 64 * 192, Bs, 6);
        __syncthreads();
        f32x4 acc[2][4] = {};
        compute192(As, Bs, acc);
#pragma unroll
        for (int nj = 0; nj < 4; ++nj) {
            const int n = nc * 64 + nj * 16 + (lane & 15);
            const float bi = f1b[n];
#pragma unroll
            for (int mi = 0; mi < 2; ++mi)
#pragma unroll
                for (int r = 0; r < 4; ++r) {
                    const int m = m0 + wave * 32 + mi * 16 + ((lane >> 4) << 2) + r;
                    const float t = acc[mi][nj][r] + bi;
                    h[(size_t)m * 768 + n] =
                        f2bf(0.5f * t * (1.0f + erff(t * 0.7071067811865475f)));
                }
        }
        __syncthreads();
    }
}

// ---------------------------------------------------------------------------
// fc2: h[M][768]bf16 @ f2wT[192][768] + f2b + x2 -> out fp32 (out may alias x2)
// K-loop BK=64; full N=192 per block so h is read exactly once.
// ---------------------------------------------------------------------------
__global__ __launch_bounds__(256) void fc2_mfma(const u16* __restrict__ h,
                                                const u16* __restrict__ f2wT,
                                                const float* __restrict__ f2b,
                                                const float* x2, float* out) {
    __shared__ __align__(16) u16 As[128 * 72];
    __shared__ __align__(16) u16 Bs[192 * 72];
    const int tid = threadIdx.x, lane = tid & 63, wave = tid >> 6;
    const int m0 = blockIdx.x * 128;
    f32x4 acc[2][12] = {};
#pragma unroll 1
    for (int kc = 0; kc < 12; ++kc) {
        const int k0 = kc * 64;
#pragma unroll
        for (int i = 0; i < 4; ++i) {
            const int c = tid + 256 * i;
            const int row = c >> 3, ko = (c & 7) * 8;
            *(uint4*)(As + row * 72 + ko) = *(const uint4*)(h + (size_t)(m0 + row) * 768 + k0 + ko);
        }
#pragma unroll
        for (int i = 0; i < 6; ++i) {
            const int c = tid + 256 * i;
            const int row = c >> 3, ko = (c & 7) * 8;
            *(uint4*)(Bs + row * 72 + ko) = *(const uint4*)(f2wT + (size_t)row * 768 + k0 + ko);
        }
        __syncthreads();
        const u16* pa = As + (wave * 32 + (lane & 15)) * 72 + (lane >> 4) * 8;
        const u16* pb = Bs + (lane & 15) * 72 + (lane >> 4) * 8;
#pragma unroll
        for (int ks = 0; ks < 2; ++ks) {
            const bf16x8 a0 = *(const bf16x8*)(pa + ks * 32);
            const bf16x8 a1 = *(const bf16x8*)(pa + 16 * 72 + ks * 32);
#pragma unroll
            for (int nj = 0; nj < 12; ++nj) {
                const bf16x8 b = *(const bf16x8*)(pb + nj * 16 * 72 + ks * 32);
                acc[0][nj] = __builtin_amdgcn_mfma_f32_16x16x32_bf16(a0, b, acc[0][nj], 0, 0, 0);
                acc[1][nj] = __builtin_amdgcn_mfma_f32_16x16x32_bf16(a1, b, acc[1][nj], 0, 0, 0);
            }
        }
        __syncthreads();
    }
#pragma unroll
    for (int nj = 0; nj < 12; ++nj) {
        const int n = nj * 16 + (lane & 15);
        const float bi = f2b[n];
#pragma unroll
        for (int mi = 0; mi < 2; ++mi)
#pragma unroll
            for (int r = 0; r < 4; ++r) {
                const int m = m0 + wave * 32 + mi * 16 + ((lane >> 4) << 2) + r;
                const size_t g = (size_t)m * C_DIM + n;
                out[g] = x2[g] + bi + acc[mi][nj][r];
            }
    }
}

// ---------------------------------------------------------------------------
// attention (vector fp32 math, bf16 I/O): one block per (win, head)
// ---------------------------------------------------------------------------
__global__ __launch_bounds__(256) void attn_kernel(const u16* __restrict__ qg,
                                                   const u16* __restrict__ kg,
                                                   const u16* __restrict__ vg,
                                                   const float* __restrict__ rpb,
                                                   u16* __restrict__ o, int shifted) {
    __shared__ float qs[64 * 33];
    __shared__ float ks[64 * 33];
    __shared__ float vs[64 * 36];
    __shared__ float ps[64 * 68];
    __shared__ float bias_s[343];
    __shared__ float inv_s[64];
    __shared__ int ms[64];
    const int tid = threadIdx.x;
    const int head = blockIdx.x >> 11;
    const int win = blockIdx.x & 2047;
    const size_t base = (size_t)(win * 6 + head) * (64 * 32);
    {
        const int f = tid * 8;
        const int n = f >> 5, hd = f & 31;
        uint4 raw = *(const uint4*)(qg + base + f);
        const u16* pr = (const u16*)&raw;
        float* p = qs + n * 33 + hd;
#pragma unroll
        for (int j = 0; j < 8; ++j) p[j] = bf2f(pr[j]);
        raw = *(const uint4*)(kg + base + f);
        p = ks + n * 33 + hd;
#pragma unroll
        for (int j = 0; j < 8; ++j) p[j] = bf2f(pr[j]);
        raw = *(const uint4*)(vg + base + f);
        p = vs + n * 36 + hd;
#pragma unroll
        for (int j = 0; j < 8; ++j) p[j] = bf2f(pr[j]);
    }
    for (int idx = tid; idx < 343; idx += 256) bias_s[idx] = rpb[idx * 6 + head];
    if (tid < 64) {
        int mv = 0;
        if (shifted) {
            const int sb = win >> 8, hb = (win >> 4) & 15, wb = win & 15;
            const int gz = sb * 4 + (tid >> 4);
            const int gy = hb * 4 + ((tid >> 2) & 3);
            const int gx = wb * 4 + (tid & 3);
            const int rz = gz < 28 ? 0 : (gz < 30 ? 1 : 2);
            const int ry = gy < 60 ? 0 : (gy < 62 ? 1 : 2);
            const int rw = gx < 60 ? 0 : (gx < 62 ? 1 : 2);
            mv = rz * 9 + ry * 3 + rw;
        }
        ms[tid] = mv;
    }
    __syncthreads();
    const int tx = tid & 15, ty = tid >> 4;
    float a16[4][4] = {};
#pragma unroll
    for (int d = 0; d < 32; ++d) {
        float qa[4], kb[4];
#pragma unroll
        for (int ii = 0; ii < 4; ++ii) qa[ii] = qs[(ty * 4 + ii) * 33 + d];
#pragma unroll
        for (int jj = 0; jj < 4; ++jj) kb[jj] = ks[(tx * 4 + jj) * 33 + d];
#pragma unroll
        for (int ii = 0; ii < 4; ++ii)
#pragma unroll
            for (int jj = 0; jj < 4; ++jj) a16[ii][jj] = fmaf(qa[ii], kb[jj], a16[ii][jj]);
    }
#pragma unroll
    for (int ii = 0; ii < 4; ++ii) {
#pragma unroll
        for (int jj = 0; jj < 4; ++jj) {
            const int i = ty * 4 + ii, j = tx * 4 + jj;
            const int dz = (i >> 4) - (j >> 4) + 3;
            const int dy = ((i >> 2) & 3) - ((j >> 2) & 3) + 3;
            const int dx = (i & 3) - (j & 3) + 3;
            float val = a16[ii][jj] + bias_s[dz * 49 + dy * 7 + dx];
            if (shifted && (ms[i] != ms[j])) val -= 100.0f;
            ps[i * 68 + j] = val;
        }
    }
    __syncthreads();
    {
        const int r = tid >> 2, sub = tid & 3;
        float* row = ps + r * 68 + sub * 16;
        float mx = -3.0e38f;
#pragma unroll
        for (int jj = 0; jj < 16; ++jj) mx = fmaxf(mx, row[jj]);
        mx = fmaxf(mx, __shfl_xor(mx, 1, 64));
        mx = fmaxf(mx, __shfl_xor(mx, 2, 64));
        float sum = 0.0f;
#pragma unroll
        for (int jj = 0; jj < 16; ++jj) {
            const float e = expf(row[jj] - mx);
            row[jj] = e;
            sum += e;
        }
        sum += __shfl_xor(sum, 1, 64);
        sum += __shfl_xor(sum, 2, 64);
        if (sub == 0) inv_s[r] = 1.0f / sum;
    }
    __syncthreads();
    {
        const int i = tid >> 2, d0 = (tid & 3) * 8;
        float av[8] = {};
        const float* prow = ps + i * 68;
#pragma unroll
        for (int j = 0; j < 64; ++j) {
            const float p = prow[j];
            const float4 va = *(const float4*)(vs + j * 36 + d0);
            const float4 vb = *(const float4*)(vs + j * 36 + d0 + 4);
            av[0] = fmaf(p, va.x, av[0]); av[1] = fmaf(p, va.y, av[1]);
            av[2] = fmaf(p, va.z, av[2]); av[3] = fmaf(p, va.w, av[3]);
            av[4] = fmaf(p, vb.x, av[4]); av[5] = fmaf(p, vb.y, av[5]);
            av[6] = fmaf(p, vb.z, av[6]); av[7] = fmaf(p, vb.w, av[7]);
        }
        const float inv = inv_s[i];
        u16 tmp[8];
#pragma unroll
        for (int j = 0; j < 8; ++j) tmp[j] = f2bf(av[j] * inv);
        *(uint4*)(o + (size_t)(win * 64 + i) * C_DIM + head * 32 + d0) = *(uint4*)tmp;
    }
}

// ---------------------------------------------------------------------------
// orchestration. ws bytes: [0,48M) A-region (xw->o->x2n bf16); q/k/v at 48/96/144M;
// h overlays q..v (dead) at 48M..240M; weights at 240M (offW). x2 = d_out fp32.
// ---------------------------------------------------------------------------
struct WOffs { size_t qwT, pwT, f1wT, f2wT; };

static void run_block(const float* X, float* XOUT,
                      const float* g1, const float* b1, const float* qb,
                      const float* rpb, const float* pb,
                      const float* g2, const float* b2,
                      const float* f1b, const float* f2b,
                      const u16* qwT, const u16* pwT, const u16* f1wT, const u16* f2wT,
                      int shifted, char* ws, hipStream_t stream) {
    const size_t PB = (size_t)L_TOK * C_DIM * sizeof(u16);  // 48 MB
    u16* xw = (u16*)ws;                 // [0,PB): xw -> o -> x2n
    u16* q  = (u16*)(ws + PB);
    u16* k  = (u16*)(ws + 2 * PB);
    u16* v  = (u16*)(ws + 3 * PB);
    u16* o   = xw;
    u16* x2n = xw;
    u16* h  = (u16*)(ws + PB);          // overlays q,k,v after attn
    float* x2 = XOUT;

    ln_kernel<<<L_TOK / 4, 256, 0, stream>>>(X, g1, b1, xw, shifted ? 1 : 0);
    qkv_mfma<<<L_TOK / 128, 256, 0, stream>>>(xw, qwT, qb, q, k, v);
    attn_kernel<<<NWIN * 6, 256, 0, stream>>>(q, k, v, rpb, o, shifted);
    proj_mfma<<<L_TOK / 128, 256, 0, stream>>>(o, pwT, pb, X, x2, shifted);
    ln_kernel<<<L_TOK / 4, 256, 0, stream>>>(x2, g2, b2, x2n, 2);
    fc1_mfma<<<L_TOK / 128, 256, 0, stream>>>(x2n, f1wT, f1b, h);
    fc2_mfma<<<L_TOK / 128, 256, 0, stream>>>(h, f2wT, f2b, x2, XOUT);
}

extern "C" void kernel_launch(void* const* d_in, const int* in_sizes, int n_in,
                              void* d_out, int out_size, void* d_ws, size_t ws_size,
                              hipStream_t stream) {
    const float* x = (const float*)d_in[0];
    float* out = (float*)d_out;
    char* ws = (char*)d_ws;
    auto in = [&](int i) { return (const float*)d_in[i]; };

    // weights region: after 48MB*5 = 240MB of activation buffers
    const size_t offW = (size_t)L_TOK * C_DIM * sizeof(u16) * 5;
    u16* wbase = (u16*)(ws + offW);
    // per-block: qwT 110592, pwT 36864, f1wT 147456, f2wT 147456 elems
    const size_t SQ = 110592, SP = 36864, SF1 = 147456, SF2 = 147456;
    const size_t WBLK = SQ + SP + SF1 + SF2;
    u16* qwT[2]  = { wbase,                    wbase + WBLK };
    u16* pwT[2]  = { wbase + SQ,               wbase + WBLK + SQ };
    u16* f1wT[2] = { wbase + SQ + SP,          wbase + WBLK + SQ + SP };
    u16* f2wT[2] = { wbase + SQ + SP + SF1,    wbase + WBLK + SQ + SP + SF1 };

    // transpose+convert all weights (inputs: qw=3/16, pw=6/19, f1w=10/23, f2w=12/25)
    wtrans_kernel<<<(192 * 576 + 255) / 256, 256, 0, stream>>>(in(3),  qwT[0],  192, 576);
    wtrans_kernel<<<(192 * 192 + 255) / 256, 256, 0, stream>>>(in(6),  pwT[0],  192, 192);
    wtrans_kernel<<<(192 * 768 + 255) / 256, 256, 0, stream>>>(in(10), f1wT[0], 192, 768);
    wtrans_kernel<<<(768 * 192 + 255) / 256, 256, 0, stream>>>(in(12), f2wT[0], 768, 192);
    wtrans_kernel<<<(192 * 576 + 255) / 256, 256, 0, stream>>>(in(16), qwT[1],  192, 576);
    wtrans_kernel<<<(192 * 192 + 255) / 256, 256, 0, stream>>>(in(19), pwT[1],  192, 192);
    wtrans_kernel<<<(192 * 768 + 255) / 256, 256, 0, stream>>>(in(23), f1wT[1], 192, 768);
    wtrans_kernel<<<(768 * 192 + 255) / 256, 256, 0, stream>>>(in(25), f2wT[1], 768, 192);

    // block 0 (not shifted): x -> d_out
    run_block(x, out, in(1), in(2), in(4), in(5), in(7), in(8), in(9), in(11), in(13),
              qwT[0], pwT[0], f1wT[0], f2wT[0], 0, ws, stream);
    // block 1 (shifted): d_out -> d_out
    run_block(out, out, in(14), in(15), in(17), in(18), in(20), in(21), in(22), in(24), in(26),
              qwT[1], pwT[1], f1wT[1], f2wT[1], 1, ws, stream);
}

// Round 4
// 1125.931 us; speedup vs baseline: 3.6203x; 1.4419x over previous
//
#include <hip/hip_runtime.h>
#include <math.h>

// Swin-3D basic layer, bf16-MFMA version (GEMMs + MFMA attention).
// S=32,H=64,W=64, C=192, NH=6, HD=32, win 4x4x4 (N=64), shift 2, NWIN=2048, L=131072.

#define L_TOK 131072
#define C_DIM 192
#define NWIN 2048

typedef unsigned int uint32;
typedef unsigned short u16;
typedef __bf16 bf16x8 __attribute__((ext_vector_type(8)));
typedef __bf16 bf16x4 __attribute__((ext_vector_type(4)));
typedef float f32x4 __attribute__((ext_vector_type(4)));

__device__ __forceinline__ u16 f2bf(float f) {
    uint32 u = __float_as_uint(f);
    u += 0x7fffu + ((u >> 16) & 1u);
    return (u16)(u >> 16);
}
__device__ __forceinline__ float bf2f(u16 h) { return __uint_as_float(((uint32)h) << 16); }

// window-ordered row r -> natural token index (rolled[g] = orig[(g+shift)%D])
__device__ __forceinline__ int win_row_to_token(int r, int shifted) {
    const int win = r >> 6, n = r & 63;
    const int sb = win >> 8, hb = (win >> 4) & 15, wb = win & 15;
    int gz = sb * 4 + (n >> 4);
    int gy = hb * 4 + ((n >> 2) & 3);
    int gx = wb * 4 + (n & 3);
    if (shifted) { gz = (gz + 2) & 31; gy = (gy + 2) & 63; gx = (gx + 2) & 63; }
    return (gz << 12) | (gy << 6) | gx;
}

// ---------------------------------------------------------------------------
// weight transpose + bf16 convert: in [K][N] fp32 -> out [N][K] bf16
// ---------------------------------------------------------------------------
__global__ __launch_bounds__(256) void wtrans_kernel(const float* __restrict__ in,
                                                     u16* __restrict__ out, int K, int N) {
    const int idx = blockIdx.x * 256 + threadIdx.x;
    if (idx < K * N) {
        const int n = idx / K, k = idx - n * K;
        out[idx] = f2bf(in[(size_t)k * N + n]);
    }
}

// ---------------------------------------------------------------------------
// LayerNorm: fp32 in -> bf16 out. mode 0 partition, 1 partition+shift, 2 identity
// ---------------------------------------------------------------------------
__global__ __launch_bounds__(256) void ln_kernel(const float* __restrict__ x,
                                                 const float* __restrict__ g,
                                                 const float* __restrict__ b,
                                                 u16* __restrict__ out, int mode) {
    const int r = blockIdx.x * 4 + (threadIdx.x >> 6);
    const int lane = threadIdx.x & 63;
    const int tin = (mode == 2) ? r : win_row_to_token(r, mode);
    const float* xr = x + (size_t)tin * C_DIM;
    const float v0 = xr[lane], v1 = xr[lane + 64], v2 = xr[lane + 128];
    float s = v0 + v1 + v2;
#pragma unroll
    for (int off = 32; off >= 1; off >>= 1) s += __shfl_xor(s, off, 64);
    const float mu = s * (1.0f / 192.0f);
    const float d0 = v0 - mu, d1 = v1 - mu, d2 = v2 - mu;
    float sq = d0 * d0 + d1 * d1 + d2 * d2;
#pragma unroll
    for (int off = 32; off >= 1; off >>= 1) sq += __shfl_xor(sq, off, 64);
    const float rstd = rsqrtf(sq * (1.0f / 192.0f) + 1e-5f);
    u16* orow = out + (size_t)r * C_DIM;
    orow[lane]       = f2bf(d0 * rstd * g[lane]       + b[lane]);
    orow[lane + 64]  = f2bf(d1 * rstd * g[lane + 64]  + b[lane + 64]);
    orow[lane + 128] = f2bf(d2 * rstd * g[lane + 128] + b[lane + 128]);
}

// ---------------------------------------------------------------------------
// shared staging helpers for K=192 tiles (row stride 200 u16)
// ---------------------------------------------------------------------------
__device__ __forceinline__ void stage_rows192(const u16* __restrict__ g, u16* __restrict__ s,
                                              int iters) {
    const int tid = threadIdx.x;
#pragma unroll
    for (int i = 0; i < iters; ++i) {
        const int c = tid + 256 * i;
        const int row = c / 24, ko = (c - row * 24) * 8;
        *(uint4*)(s + row * 200 + ko) = *(const uint4*)(g + (size_t)row * 192 + ko);
    }
}

__device__ __forceinline__ void compute192(const u16* __restrict__ As, const u16* __restrict__ Bs,
                                           f32x4 (&acc)[2][4]) {
    const int lane = threadIdx.x & 63, wave = threadIdx.x >> 6;
    const u16* pa = As + (wave * 32 + (lane & 15)) * 200 + ((lane >> 4) * 8);
    const u16* pb = Bs + (lane & 15) * 200 + ((lane >> 4) * 8);
#pragma unroll
    for (int ks = 0; ks < 6; ++ks) {
        const bf16x8 a0 = *(const bf16x8*)(pa + ks * 32);
        const bf16x8 a1 = *(const bf16x8*)(pa + 16 * 200 + ks * 32);
#pragma unroll
        for (int nj = 0; nj < 4; ++nj) {
            const bf16x8 b = *(const bf16x8*)(pb + nj * 16 * 200 + ks * 32);
            acc[0][nj] = __builtin_amdgcn_mfma_f32_16x16x32_bf16(a0, b, acc[0][nj], 0, 0, 0);
            acc[1][nj] = __builtin_amdgcn_mfma_f32_16x16x32_bf16(a1, b, acc[1][nj], 0, 0, 0);
        }
    }
}

// ---------------------------------------------------------------------------
// QKV: xw[M][192]bf16 @ qwT[576][192] -> q,k,v bf16 [win*6+head][64][32], q scaled
// ---------------------------------------------------------------------------
__global__ __launch_bounds__(256) void qkv_mfma(const u16* __restrict__ xw,
                                                const u16* __restrict__ qwT,
                                                const float* __restrict__ qb,
                                                u16* __restrict__ q, u16* __restrict__ k,
                                                u16* __restrict__ v) {
    __shared__ __align__(16) u16 As[128 * 200];
    __shared__ __align__(16) u16 Bs[64 * 200];
    const int m0 = blockIdx.x * 128;
    const int lane = threadIdx.x & 63, wave = threadIdx.x >> 6;
    stage_rows192(xw + (size_t)m0 * 192, As, 12);
#pragma unroll 1
    for (int nc = 0; nc < 9; ++nc) {
        stage_rows192(qwT + (size_t)nc * 64 * 192, Bs, 6);
        __syncthreads();
        f32x4 acc[2][4] = {};
        compute192(As, Bs, acc);
#pragma unroll
        for (int nj = 0; nj < 4; ++nj) {
            const int n = nc * 64 + nj * 16 + (lane & 15);
            const int which = n / 192;
            const int hn = n - which * 192;
            const int head = hn >> 5, hd = hn & 31;
            u16* dst = (which == 0) ? q : (which == 1) ? k : v;
            const float sc = (which == 0) ? 0.17677669529663687f : 1.0f;
            const float bi = qb[n];
#pragma unroll
            for (int mi = 0; mi < 2; ++mi)
#pragma unroll
                for (int r = 0; r < 4; ++r) {
                    const int m = m0 + wave * 32 + mi * 16 + ((lane >> 4) << 2) + r;
                    const int win = m >> 6, tok = m & 63;
                    dst[((size_t)(win * 6 + head) * 64 + tok) * 32 + hd] =
                        f2bf((acc[mi][nj][r] + bi) * sc);
                }
        }
        __syncthreads();
    }
}

// ---------------------------------------------------------------------------
// proj: o[M][192]bf16 @ pwT[192][192] + pb + X(residual) -> x2 fp32 (win-reverse)
// ---------------------------------------------------------------------------
__global__ __launch_bounds__(256) void proj_mfma(const u16* __restrict__ o,
                                                 const u16* __restrict__ pwT,
                                                 const float* __restrict__ pb,
                                                 const float* xin, float* x2, int shifted) {
    __shared__ __align__(16) u16 As[128 * 200];
    __shared__ __align__(16) u16 Bs[64 * 200];
    const int m0 = blockIdx.x * 128;
    const int lane = threadIdx.x & 63, wave = threadIdx.x >> 6;
    stage_rows192(o + (size_t)m0 * 192, As, 12);
#pragma unroll 1
    for (int nc = 0; nc < 3; ++nc) {
        stage_rows192(pwT + (size_t)nc * 64 * 192, Bs, 6);
        __syncthreads();
        f32x4 acc[2][4] = {};
        compute192(As, Bs, acc);
#pragma unroll
        for (int nj = 0; nj < 4; ++nj) {
            const int n = nc * 64 + nj * 16 + (lane & 15);
            const float bi = pb[n];
#pragma unroll
            for (int mi = 0; mi < 2; ++mi)
#pragma unroll
                for (int r = 0; r < 4; ++r) {
                    const int m = m0 + wave * 32 + mi * 16 + ((lane >> 4) << 2) + r;
                    const int t = win_row_to_token(m, shifted);
                    const size_t gdx = (size_t)t * C_DIM + n;
                    x2[gdx] = xin[gdx] + bi + acc[mi][nj][r];
                }
        }
        __syncthreads();
    }
}

// ---------------------------------------------------------------------------
// fc1: x2n[M][192]bf16 @ f1wT[768][192] + f1b, exact gelu -> h[M][768] bf16
// ---------------------------------------------------------------------------
__global__ __launch_bounds__(256) void fc1_mfma(const u16* __restrict__ x2n,
                                                const u16* __restrict__ f1wT,
                                                const float* __restrict__ f1b,
                                                u16* __restrict__ h) {
    __shared__ __align__(16) u16 As[128 * 200];
    __shared__ __align__(16) u16 Bs[64 * 200];
    const int m0 = blockIdx.x * 128;
    const int lane = threadIdx.x & 63, wave = threadIdx.x >> 6;
    stage_rows192(x2n + (size_t)m0 * 192, As, 12);
#pragma unroll 1
    for (int nc = 0; nc < 12; ++nc) {
        stage_rows192(f1wT + (size_t)nc * 64 * 192, Bs, 6);
        __syncthreads();
        f32x4 acc[2][4] = {};
        compute192(As, Bs, acc);
#pragma unroll
        for (int nj = 0; nj < 4; ++nj) {
            const int n = nc * 64 + nj * 16 + (lane & 15);
            const float bi = f1b[n];
#pragma unroll
            for (int mi = 0; mi < 2; ++mi)
#pragma unroll
                for (int r = 0; r < 4; ++r) {
                    const int m = m0 + wave * 32 + mi * 16 + ((lane >> 4) << 2) + r;
                    const float t = acc[mi][nj][r] + bi;
                    h[(size_t)m * 768 + n] =
                        f2bf(0.5f * t * (1.0f + erff(t * 0.7071067811865475f)));
                }
        }
        __syncthreads();
    }
}

// ---------------------------------------------------------------------------
// fc2: h[M][768]bf16 @ f2wT[192][768] + f2b + x2 -> out fp32 (out may alias x2)
// ---------------------------------------------------------------------------
__global__ __launch_bounds__(256) void fc2_mfma(const u16* __restrict__ h,
                                                const u16* __restrict__ f2wT,
                                                const float* __restrict__ f2b,
                                                const float* x2, float* out) {
    __shared__ __align__(16) u16 As[128 * 72];
    __shared__ __align__(16) u16 Bs[192 * 72];
    const int tid = threadIdx.x, lane = tid & 63, wave = tid >> 6;
    const int m0 = blockIdx.x * 128;
    f32x4 acc[2][12] = {};
#pragma unroll 1
    for (int kc = 0; kc < 12; ++kc) {
        const int k0 = kc * 64;
#pragma unroll
        for (int i = 0; i < 4; ++i) {
            const int c = tid + 256 * i;
            const int row = c >> 3, ko = (c & 7) * 8;
            *(uint4*)(As + row * 72 + ko) = *(const uint4*)(h + (size_t)(m0 + row) * 768 + k0 + ko);
        }
#pragma unroll
        for (int i = 0; i < 6; ++i) {
            const int c = tid + 256 * i;
            const int row = c >> 3, ko = (c & 7) * 8;
            *(uint4*)(Bs + row * 72 + ko) = *(const uint4*)(f2wT + (size_t)row * 768 + k0 + ko);
        }
        __syncthreads();
        const u16* pa = As + (wave * 32 + (lane & 15)) * 72 + (lane >> 4) * 8;
        const u16* pb = Bs + (lane & 15) * 72 + (lane >> 4) * 8;
#pragma unroll
        for (int ks = 0; ks < 2; ++ks) {
            const bf16x8 a0 = *(const bf16x8*)(pa + ks * 32);
            const bf16x8 a1 = *(const bf16x8*)(pa + 16 * 72 + ks * 32);
#pragma unroll
            for (int nj = 0; nj < 12; ++nj) {
                const bf16x8 b = *(const bf16x8*)(pb + nj * 16 * 72 + ks * 32);
                acc[0][nj] = __builtin_amdgcn_mfma_f32_16x16x32_bf16(a0, b, acc[0][nj], 0, 0, 0);
                acc[1][nj] = __builtin_amdgcn_mfma_f32_16x16x32_bf16(a1, b, acc[1][nj], 0, 0, 0);
            }
        }
        __syncthreads();
    }
#pragma unroll
    for (int nj = 0; nj < 12; ++nj) {
        const int n = nj * 16 + (lane & 15);
        const float bi = f2b[n];
#pragma unroll
        for (int mi = 0; mi < 2; ++mi)
#pragma unroll
            for (int r = 0; r < 4; ++r) {
                const int m = m0 + wave * 32 + mi * 16 + ((lane >> 4) << 2) + r;
                const size_t g = (size_t)m * C_DIM + n;
                out[g] = x2[g] + bi + acc[mi][nj][r];
            }
    }
}

// ---------------------------------------------------------------------------
// MFMA attention: one block per (win, head), 4 waves.
// Swapped QK^T (S^T = mfma(K, Q)) so softmax is lane-local per q-row.
// Q/K fragments loaded directly from global (coalesced); V transposed in LDS.
// ---------------------------------------------------------------------------
__global__ __launch_bounds__(256) void attn_mfma(const u16* __restrict__ qg,
                                                 const u16* __restrict__ kg,
                                                 const u16* __restrict__ vg,
                                                 const float* __restrict__ rpb,
                                                 u16* __restrict__ o, int shifted) {
    __shared__ __align__(16) u16 vt[32 * 68];   // V^T: vt[d][tok]
    __shared__ __align__(16) u16 ps[64 * 68];   // P bf16, per-wave-private rows
    __shared__ __align__(16) u16 os[64 * 40];   // O staging for coalesced writes
    __shared__ float bias_s[343];
    __shared__ int ms[64];
    const int tid = threadIdx.x;
    const int lane = tid & 63, w = tid >> 6;
    const int i = lane & 15, g = lane >> 4;
    const int head = blockIdx.x >> 11;
    const int win = blockIdx.x & 2047;
    const size_t base = (size_t)(win * 6 + head) * 2048;

    // load Q (B-frag, this wave's 16 q-rows) and K (A-frags, all 64 k-rows): coalesced 16B
    const bf16x8 qf = *(const bf16x8*)(qg + base + (size_t)(16 * w + i) * 32 + 8 * g);
    bf16x8 kf[4];
#pragma unroll
    for (int t = 0; t < 4; ++t)
        kf[t] = *(const bf16x8*)(kg + base + (size_t)(16 * t + i) * 32 + 8 * g);

    // stage V transposed: vt[d][tok]
    {
        const int n = tid >> 2, c0 = (tid & 3) * 8;
        uint4 raw = *(const uint4*)(vg + base + (size_t)n * 32 + c0);
        const u16* pr = (const u16*)&raw;
#pragma unroll
        for (int j = 0; j < 8; ++j) vt[(c0 + j) * 68 + n] = pr[j];
    }
    for (int idx = tid; idx < 343; idx += 256) bias_s[idx] = rpb[idx * 6 + head];
    if (tid < 64) {
        int mv = 0;
        if (shifted) {
            const int sb = win >> 8, hb = (win >> 4) & 15, wb = win & 15;
            const int gz = sb * 4 + (tid >> 4);
            const int gy = hb * 4 + ((tid >> 2) & 3);
            const int gx = wb * 4 + (tid & 3);
            const int rz = gz < 28 ? 0 : (gz < 30 ? 1 : 2);
            const int ry = gy < 60 ? 0 : (gy < 62 ? 1 : 2);
            const int rw = gx < 60 ? 0 : (gx < 62 ? 1 : 2);
            mv = rz * 9 + ry * 3 + rw;
        }
        ms[tid] = mv;
    }
    __syncthreads();

    // QK^T swapped: s[t] = mfma(K-tile t, Q) -> lane holds S[q=16w+i][k=16t+4g+r]
    const f32x4 zero = {0.0f, 0.0f, 0.0f, 0.0f};
    f32x4 s[4];
#pragma unroll
    for (int t = 0; t < 4; ++t)
        s[t] = __builtin_amdgcn_mfma_f32_16x16x32_bf16(kf[t], qf, zero, 0, 0, 0);

    const int qrow = 16 * w + i;
    const int mq = ms[qrow];
    float p[16];
#pragma unroll
    for (int t = 0; t < 4; ++t)
#pragma unroll
        for (int r = 0; r < 4; ++r) {
            const int j = 16 * t + 4 * g + r;
            const int dz = (qrow >> 4) - (j >> 4) + 3;
            const int dy = ((qrow >> 2) & 3) - ((j >> 2) & 3) + 3;
            const int dx = (qrow & 3) - (j & 3) + 3;
            float val = s[t][r] + bias_s[dz * 49 + dy * 7 + dx];
            if (shifted && (mq != ms[j])) val -= 100.0f;
            p[t * 4 + r] = val;
        }
    // softmax over the 64 k-cols: 16 regs + lanes {i, i+16, i+32, i+48}
    float mx = -3.0e38f;
#pragma unroll
    for (int u = 0; u < 16; ++u) mx = fmaxf(mx, p[u]);
    mx = fmaxf(mx, __shfl_xor(mx, 16, 64));
    mx = fmaxf(mx, __shfl_xor(mx, 32, 64));
    float sum = 0.0f;
#pragma unroll
    for (int u = 0; u < 16; ++u) { p[u] = expf(p[u] - mx); sum += p[u]; }
    sum += __shfl_xor(sum, 16, 64);
    sum += __shfl_xor(sum, 32, 64);
    const float inv = 1.0f / sum;

    // write P (unnormalized) as bf16 into per-wave-private ps rows
#pragma unroll
    for (int t = 0; t < 4; ++t) {
        ushort4 pk;
        pk.x = f2bf(p[t * 4 + 0]); pk.y = f2bf(p[t * 4 + 1]);
        pk.z = f2bf(p[t * 4 + 2]); pk.w = f2bf(p[t * 4 + 3]);
        *(ushort4*)(ps + (size_t)qrow * 68 + 16 * t + 4 * g) = pk;
    }

    // PV: O[16w+..][d] ; A = P rows (own wave's ps region), B = V^T
    f32x4 oacc[2] = {zero, zero};
#pragma unroll
    for (int kb = 0; kb < 2; ++kb) {
        const bf16x4 alo = *(const bf16x4*)(ps + (size_t)qrow * 68 + 8 * g + 32 * kb);
        const bf16x4 ahi = *(const bf16x4*)(ps + (size_t)qrow * 68 + 8 * g + 32 * kb + 4);
        const bf16x8 a = __builtin_shufflevector(alo, ahi, 0, 1, 2, 3, 4, 5, 6, 7);
#pragma unroll
        for (int ct = 0; ct < 2; ++ct) {
            const bf16x4 blo = *(const bf16x4*)(vt + (size_t)(i + 16 * ct) * 68 + 8 * g + 32 * kb);
            const bf16x4 bhi = *(const bf16x4*)(vt + (size_t)(i + 16 * ct) * 68 + 8 * g + 32 * kb + 4);
            const bf16x8 b = __builtin_shufflevector(blo, bhi, 0, 1, 2, 3, 4, 5, 6, 7);
            oacc[ct] = __builtin_amdgcn_mfma_f32_16x16x32_bf16(a, b, oacc[ct], 0, 0, 0);
        }
    }
    // scale rows by their 1/sum (row 16w+4g+r's inv lives in lane 4g+r) and stage O
#pragma unroll
    for (int ct = 0; ct < 2; ++ct)
#pragma unroll
        for (int r = 0; r < 4; ++r) {
            const float ov = oacc[ct][r] * __shfl(inv, 4 * g + r, 64);
            os[(16 * w + 4 * g + r) * 40 + i + 16 * ct] = f2bf(ov);
        }
    __syncthreads();
    // coalesced global write
    {
        const int n = tid >> 2, c0 = (tid & 3) * 8;
        const uint4 val = *(const uint4*)(os + n * 40 + c0);
        *(uint4*)(o + (size_t)(win * 64 + n) * C_DIM + head * 32 + c0) = val;
    }
}

// ---------------------------------------------------------------------------
// orchestration. ws bytes: [0,48M) A-region (xw->o->x2n bf16); q/k/v at 48/96/144M;
// h overlays q..v (dead) at 48M..240M; weights at 240M. x2 = d_out fp32.
// ---------------------------------------------------------------------------
static void run_block(const float* X, float* XOUT,
                      const float* g1, const float* b1, const float* qb,
                      const float* rpb, const float* pb,
                      const float* g2, const float* b2,
                      const float* f1b, const float* f2b,
                      const u16* qwT, const u16* pwT, const u16* f1wT, const u16* f2wT,
                      int shifted, char* ws, hipStream_t stream) {
    const size_t PB = (size_t)L_TOK * C_DIM * sizeof(u16);  // 48 MB
    u16* xw = (u16*)ws;                 // [0,PB): xw -> o -> x2n
    u16* q  = (u16*)(ws + PB);
    u16* k  = (u16*)(ws + 2 * PB);
    u16* v  = (u16*)(ws + 3 * PB);
    u16* o   = xw;
    u16* x2n = xw;
    u16* h  = (u16*)(ws + PB);          // overlays q,k,v after attn
    float* x2 = XOUT;

    ln_kernel<<<L_TOK / 4, 256, 0, stream>>>(X, g1, b1, xw, shifted ? 1 : 0);
    qkv_mfma<<<L_TOK / 128, 256, 0, stream>>>(xw, qwT, qb, q, k, v);
    attn_mfma<<<NWIN * 6, 256, 0, stream>>>(q, k, v, rpb, o, shifted);
    proj_mfma<<<L_TOK / 128, 256, 0, stream>>>(o, pwT, pb, X, x2, shifted);
    ln_kernel<<<L_TOK / 4, 256, 0, stream>>>(x2, g2, b2, x2n, 2);
    fc1_mfma<<<L_TOK / 128, 256, 0, stream>>>(x2n, f1wT, f1b, h);
    fc2_mfma<<<L_TOK / 128, 256, 0, stream>>>(h, f2wT, f2b, x2, XOUT);
}

extern "C" void kernel_launch(void* const* d_in, const int* in_sizes, int n_in,
                              void* d_out, int out_size, void* d_ws, size_t ws_size,
                              hipStream_t stream) {
    const float* x = (const float*)d_in[0];
    float* out = (float*)d_out;
    char* ws = (char*)d_ws;
    auto in = [&](int i) { return (const float*)d_in[i]; };

    const size_t offW = (size_t)L_TOK * C_DIM * sizeof(u16) * 5;
    u16* wbase = (u16*)(ws + offW);
    const size_t SQ = 110592, SP = 36864, SF1 = 147456, SF2 = 147456;
    const size_t WBLK = SQ + SP + SF1 + SF2;
    u16* qwT[2]  = { wbase,                    wbase + WBLK };
    u16* pwT[2]  = { wbase + SQ,               wbase + WBLK + SQ };
    u16* f1wT[2] = { wbase + SQ + SP,          wbase + WBLK + SQ + SP };
    u16* f2wT[2] = { wbase + SQ + SP + SF1,    wbase + WBLK + SQ + SP + SF1 };

    wtrans_kernel<<<(192 * 576 + 255) / 256, 256, 0, stream>>>(in(3),  qwT[0],  192, 576);
    wtrans_kernel<<<(192 * 192 + 255) / 256, 256, 0, stream>>>(in(6),  pwT[0],  192, 192);
    wtrans_kernel<<<(192 * 768 + 255) / 256, 256, 0, stream>>>(in(10), f1wT[0], 192, 768);
    wtrans_kernel<<<(768 * 192 + 255) / 256, 256, 0, stream>>>(in(12), f2wT[0], 768, 192);
    wtrans_kernel<<<(192 * 576 + 255) / 256, 256, 0, stream>>>(in(16), qwT[1],  192, 576);
    wtrans_kernel<<<(192 * 192 + 255) / 256, 256, 0, stream>>>(in(19), pwT[1],  192, 192);
    wtrans_kernel<<<(192 * 768 + 255) / 256, 256, 0, stream>>>(in(23), f1wT[1], 192, 768);
    wtrans_kernel<<<(768 * 192 + 255) / 256, 256, 0, stream>>>(in(25), f2wT[1], 768, 192);

    run_block(x, out, in(1), in(2), in(4), in(5), in(7), in(8), in(9), in(11), in(13),
              qwT[0], pwT[0], f1wT[0], f2wT[0], 0, ws, stream);
    run_block(out, out, in(14), in(15), in(17), in(18), in(20), in(21), in(22), in(24), in(26),
              qwT[1], pwT[1], f1wT[1], f2wT[1], 1, ws, stream);
}